// Round 9
// baseline (48.199 us; speedup 1.0000x reference)
//
#include <hip/hip_runtime.h>

// 2D Gaussian splatting renderer, MI355X. R12 (DIAGNOSTIC).
// N=4096 gaussians, 512x512x3 fp32 image, 64 tiles of 64x64 px.
//
// R12 theory: R11 ~= R10 (33.6 vs 34.0) despite 2x waves/SIMD -> render is
// NOT latency-bound; binder is VALU-issue vs LDS-pipe vs the ~11us fixed
// block -- indistinguishable from dur alone, and render (<38us) never shows
// in top-5 (ws-poison fills ~38.5us crowd it out). This round BUYS the
// measurement: blend phase runs TWICE in-kernel (rep0 discarded via opaque
// t_init + asm keep-alive; per-rep LDS staging writes firewall CSE; rep1
// bit-identical to R11). Render dur ~doubles -> enters top-5 WITH
// VALUBusy/Occupancy/LDS_BANK_CONFLICT, and dur(R12)-dur(R11) = render.
// Checked-and-killed levers: per-px early-exit (0.01 alpha floor => seg-
// local T reaches only ~0.16 at len 49; 8-seg split makes exit unreachable);
// preprocess-into-render fusion (per-block redundant rank ~= launch saving).

#define N_G    4096
#define W_IMG  512
#define TL_    64
#define NTILES 64
#define LOG2E  1.44269504088896340736f

typedef float v2f __attribute__((ext_vector_type(2)));

// ws layout (bytes):
//   [0,      65536) : float4 a4[N_G] = {px, py, qa, qb}   (depth-sorted)
//   [65536, 131072) : float4 b4[N_G] = {qc, lb, cr, cg}
//   [131072,147456) : float  c1[N_G]  = cb
//   [147456,180224) : u64    tmask[N_G] = tile-overlap bitmask (bit tx*8+ty)

__global__ __launch_bounds__(256)
void gs_preprocess(const float* __restrict__ pos2d,
                   const float* __restrict__ cov2d,
                   const float* __restrict__ opacity,
                   const float* __restrict__ color,
                   float4* __restrict__ a4,
                   float4* __restrict__ b4,
                   float* __restrict__ c1,
                   unsigned long long* __restrict__ tmask) {
    __shared__ __align__(16) float s_depth[N_G];
    const int t = threadIdx.x;

    for (int k = t; k < N_G; k += 256)
        s_depth[k] = pos2d[k * 3 + 2];
    __syncthreads();

    const int g = t >> 5;                  // 8 gaussian slots per block
    const int s = t & 31;                  // 32-way j partition per gaussian
    const int i = blockIdx.x * 8 + g;      // 512 blocks x 8 = 4096
    const float di = s_depth[i];

    const float4* s_d4 = (const float4*)s_depth;
    int rank = 0;
    #pragma unroll 8
    for (int k = 0; k < 32; ++k) {
        const int j4 = s + 32 * k;
        const float4 d = s_d4[j4];
        const int j = 4 * j4;
        rank += (d.x < di) || (d.x == di && (j + 0) < i);   // stable argsort
        rank += (d.y < di) || (d.y == di && (j + 1) < i);
        rank += (d.z < di) || (d.z == di && (j + 2) < i);
        rank += (d.w < di) || (d.w == di && (j + 3) < i);
    }
    rank += __shfl_xor(rank, 1);
    rank += __shfl_xor(rank, 2);
    rank += __shfl_xor(rank, 4);
    rank += __shfl_xor(rank, 8);
    rank += __shfl_xor(rank, 16);

    if (s == 0) {
        const float px = pos2d[i * 3 + 0];
        const float py = pos2d[i * 3 + 1];
        const float a = cov2d[i * 4 + 0];
        const float b = cov2d[i * 4 + 1];
        const float c = cov2d[i * 4 + 2];
        const float d = cov2d[i * 4 + 3];

        const float trace = a + d;
        const float det = a * d - b * c;
        const float tmp = trace * trace - 4.0f * det;
        const float term2 = 0.5f * sqrtf(fmaxf(tmp, 0.0f));
        const float radius = 3.0f * sqrtf(fmaxf(0.5f * trace - term2, 0.5f * trace + term2));
        const float inv_det = 1.0f / det;
        const float ia  = d * inv_det;
        const float ibc = (-b * inv_det) + (-c * inv_det);  // match ref's ib+ic rounding
        const float idd = a * inv_det;

        const float op = opacity[i];
        const float cr = fmaxf(color[i * 3 + 0] + 0.5f, 0.0f);
        const float cg = fmaxf(color[i * 3 + 1] + 0.5f, 0.0f);
        const float cb = fmaxf(color[i * 3 + 2] + 0.5f, 0.0f);

        // Tile-overlap bitmask, bit (tx*8+ty); comparisons IDENTICAL to the
        // reference cull so the listed set matches exactly.
        unsigned int xm = 0, ym = 0;
        #pragma unroll
        for (int tc = 0; tc < 8; ++tc) {
            const float lo = (float)(tc * TL_);
            if ((px + radius >= lo) && (px - radius < lo + (float)TL_)) xm |= 1u << tc;
            if ((py + radius >= lo) && (py - radius < lo + (float)TL_)) ym |= 1u << tc;
        }
        unsigned long long m = 0ull;
        #pragma unroll
        for (int tc = 0; tc < 8; ++tc)
            if (xm & (1u << tc)) m |= (unsigned long long)ym << (8 * tc);

        a4[rank] = make_float4(px, py, -0.5f * ia * LOG2E, -0.5f * ibc * LOG2E);
        b4[rank] = make_float4(-0.5f * idd * LOG2E, __log2f(op), cr, cg);
        c1[rank] = cb;
        tmask[rank] = m;
    }
}

__global__ __launch_bounds__(512, 4)
void gs_render(const float4* __restrict__ a4,
               const float4* __restrict__ b4,
               const float* __restrict__ c1,
               const unsigned long long* __restrict__ tmask,
               float* __restrict__ out) {
    // 512 blocks x 512 threads (8 waves). Block covers 8 px in X, 64 in Y.
    // Wave w = depth-segment w over the same 512-px patch. DIAGNOSTIC: the
    // whole blend runs twice (rep0 kept alive but discarded).
    __shared__ unsigned short s_list[N_G];
    __shared__ int s_wcnt[8];
    __shared__ __align__(16) float4 s_wa[8][64];
    __shared__ __align__(16) float4 s_wb[8][64];
    __shared__ float s_wc[8][64];
    __shared__ __align__(16) float4 s_m[4][512];

    const int id = blockIdx.x;
    const int sub  = id >> 6;              // 0..7 (X octant)
    const int tile = ((id & 63) * 21 + sub * 11) & 63;
    const int tx = tile >> 3;
    const int ty = tile & 7;
    const int t = threadIdx.x;
    const int wave = t >> 6;               // 0..7
    const int lane = t & 63;

    // ---- cull via tile mask (2-pass cross-wave-stable compaction)
    unsigned int bits = 0;
    int wcnt = 0;
    #pragma unroll 4
    for (int it = 0; it < 8; ++it) {
        const int g = wave * 512 + it * 64 + lane;
        const bool m = (tmask[g] >> tile) & 1ull;
        bits |= (m ? 1u : 0u) << it;
        wcnt += __popcll(__ballot(m));
    }
    if (lane == 0) s_wcnt[wave] = wcnt;
    __syncthreads();
    int total = 0, base = 0;
    #pragma unroll
    for (int w = 0; w < 8; ++w) {
        const int c = s_wcnt[w];
        total += c;
        if (w < wave) base += c;
    }
    #pragma unroll 4
    for (int it = 0; it < 8; ++it) {
        const bool m = (bits >> it) & 1u;
        const unsigned long long bal = __ballot(m);
        const int prefix = __popcll(bal & ((1ULL << lane) - 1ULL));
        if (m) s_list[base + prefix] = (unsigned short)(wave * 512 + it * 64 + lane);
        base += __popcll(bal);
    }
    __syncthreads();   // s_list complete; no barriers until merge

    const int s0 = (wave * total) >> 3;
    const int s1 = ((wave + 1) * total) >> 3;

    const int X0 = tx * TL_ + sub * 8;
    const int Y  = ty * TL_ + lane;
    const float fY = (float)Y;

    const v2f fX0 = {(float)(X0 + 0), (float)(X0 + 1)};
    const v2f fX1 = {(float)(X0 + 2), (float)(X0 + 3)};
    const v2f fX2 = {(float)(X0 + 4), (float)(X0 + 5)};
    const v2f fX3 = {(float)(X0 + 6), (float)(X0 + 7)};

    float4* const wa = s_wa[wave];
    float4* const wb = s_wb[wave];
    float*  const wc = s_wc[wave];

    // Opaque 1.0f: prevents GVN collapsing rep1 into rep0 (value is 1.0 at
    // runtime, so rep1's math is bit-identical to the single-pass kernel).
    float t_init = 1.0f;
    asm volatile("" : "+v"(t_init));

    v2f R0, R1, R2, R3, G0, G1, G2, G3, B0, B1, B2, B3, T0, T1, T2, T3;

    #pragma unroll 1
    for (int rep = 0; rep < 2; ++rep) {
        R0 = (v2f){0.f, 0.f}; R1 = R0; R2 = R0; R3 = R0;
        G0 = R0; G1 = R0; G2 = R0; G3 = R0;
        B0 = R0; B1 = R0; B2 = R0; B3 = R0;
        T0 = (v2f){t_init, t_init}; T1 = T0; T2 = T0; T3 = T0;

        // prologue: load first chunk (scattered gather, global->VGPR)
        float4 va, vb;
        float vc = 0.f;
        if (s0 + lane < s1) {
            const int g = s_list[s0 + lane];
            va = a4[g]; vb = b4[g]; vc = c1[g];
        }

        for (int c = s0; c < s1; c += 64) {
            const int n = min(64, s1 - c);
            if (lane < n) { wa[lane] = va; wb[lane] = vb; wc[lane] = vc; }
            const int cn = c + 64;
            if (cn + lane < s1) {
                const int g = s_list[cn + lane];
                va = a4[g]; vb = b4[g]; vc = c1[g];
            }
            #pragma unroll 4
            for (int k = 0; k < n; ++k) {
                const float4 A  = wa[k];   // px, py, qa, qb
                const float4 Bv = wb[k];   // qc, lb, cr, cg
                const float cbv = wc[k];

                const float dy   = fY - A.y;
                const float qbdy = A.w * dy;
                const float bse  = Bv.x * dy * dy + Bv.y;      // qc*dy^2 + lb
                const v2f az2 = {A.z, A.z};
                const v2f ax2 = {A.x, A.x};
                const v2f qb2 = {qbdy, qbdy};
                const v2f bs2 = {bse, bse};
                const v2f lo2 = {0.01f, 0.01f};
                const v2f hi2 = {0.99f, 0.99f};
                const v2f cr2 = {Bv.z, Bv.z};
                const v2f cg2 = {Bv.w, Bv.w};
                const v2f cb2 = {cbv, cbv};
#define PX_PAIR(FXP, Tp, Rp, Gp, Bp)                                          \
                {                                                             \
                    const v2f dx = FXP - ax2;                                 \
                    v2f q = __builtin_elementwise_fma(az2, dx, qb2);          \
                    q = __builtin_elementwise_fma(q, dx, bs2);                \
                    v2f e;                                                    \
                    e.x = exp2f(q.x); e.y = exp2f(q.y);                       \
                    v2f al;                                                   \
                    al.x = __builtin_amdgcn_fmed3f(e.x, lo2.x, hi2.x);        \
                    al.y = __builtin_amdgcn_fmed3f(e.y, lo2.y, hi2.y);        \
                    const v2f w_ = al * Tp;                                   \
                    Rp = __builtin_elementwise_fma(w_, cr2, Rp);              \
                    Gp = __builtin_elementwise_fma(w_, cg2, Gp);              \
                    Bp = __builtin_elementwise_fma(w_, cb2, Bp);              \
                    Tp = Tp - w_;                                             \
                }
                PX_PAIR(fX0, T0, R0, G0, B0)
                PX_PAIR(fX1, T1, R1, G1, B1)
                PX_PAIR(fX2, T2, R2, G2, B2)
                PX_PAIR(fX3, T3, R3, G3, B3)
#undef PX_PAIR
            }
        }

        if (rep == 0) {
            // keep rep0 fully alive (no DCE), then discard.
            float keep = T0.x + T0.y + T1.x + T1.y + T2.x + T2.y + T3.x + T3.y;
            keep += R0.x + R0.y + R1.x + R1.y + R2.x + R2.y + R3.x + R3.y;
            keep += G0.x + G0.y + G1.x + G1.y + G2.x + G2.y + G3.x + G3.y;
            keep += B0.x + B0.y + B1.x + B1.y + B2.x + B2.y + B3.x + B3.y;
            asm volatile("" :: "v"(keep));
        }
    }

    // ---- 3-round tree merge (uses rep1 finals)
#define PUBLISH(buf)                                                          \
    {                                                                         \
        (buf)[0 * 64 + lane] = make_float4(R0.x, G0.x, B0.x, T0.x);           \
        (buf)[1 * 64 + lane] = make_float4(R0.y, G0.y, B0.y, T0.y);           \
        (buf)[2 * 64 + lane] = make_float4(R1.x, G1.x, B1.x, T1.x);           \
        (buf)[3 * 64 + lane] = make_float4(R1.y, G1.y, B1.y, T1.y);           \
        (buf)[4 * 64 + lane] = make_float4(R2.x, G2.x, B2.x, T2.x);           \
        (buf)[5 * 64 + lane] = make_float4(R2.y, G2.y, B2.y, T2.y);           \
        (buf)[6 * 64 + lane] = make_float4(R3.x, G3.x, B3.x, T3.x);           \
        (buf)[7 * 64 + lane] = make_float4(R3.y, G3.y, B3.y, T3.y);           \
    }
#define COMPOSE(buf)                                                          \
    {                                                                         \
        _Pragma("unroll")                                                     \
        for (int j = 0; j < 4; ++j) {                                         \
            const float4 m0 = (buf)[(2 * j + 0) * 64 + lane];                 \
            const float4 m1 = (buf)[(2 * j + 1) * 64 + lane];                 \
            const v2f mr = {m0.x, m1.x};                                      \
            const v2f mg = {m0.y, m1.y};                                      \
            const v2f mb = {m0.z, m1.z};                                      \
            const v2f mt = {m0.w, m1.w};                                      \
            v2f* Rj = j == 0 ? &R0 : j == 1 ? &R1 : j == 2 ? &R2 : &R3;       \
            v2f* Gj = j == 0 ? &G0 : j == 1 ? &G1 : j == 2 ? &G2 : &G3;       \
            v2f* Bj = j == 0 ? &B0 : j == 1 ? &B1 : j == 2 ? &B2 : &B3;       \
            v2f* Tj = j == 0 ? &T0 : j == 1 ? &T1 : j == 2 ? &T2 : &T3;       \
            *Rj = __builtin_elementwise_fma(*Tj, mr, *Rj);                    \
            *Gj = __builtin_elementwise_fma(*Tj, mg, *Gj);                    \
            *Bj = __builtin_elementwise_fma(*Tj, mb, *Bj);                    \
            *Tj = *Tj * mt;                                                   \
        }                                                                     \
    }

    if (wave & 1) PUBLISH(s_m[wave >> 1]);
    __syncthreads();
    if (!(wave & 1)) COMPOSE(s_m[wave >> 1]);
    if (wave == 2) PUBLISH(s_m[1]);
    if (wave == 6) PUBLISH(s_m[3]);
    __syncthreads();
    if (wave == 0) COMPOSE(s_m[1]);
    if (wave == 4) COMPOSE(s_m[3]);
    if (wave == 4) PUBLISH(s_m[3]);
    __syncthreads();
    if (wave == 0) {
        COMPOSE(s_m[3]);
#define OUT_PX(i, rv, gv, bv)                                                 \
        {                                                                     \
            const int o = ((X0 + (i)) * W_IMG + Y) * 3;                       \
            out[o + 0] = rv;                                                  \
            out[o + 1] = gv;                                                  \
            out[o + 2] = bv;                                                  \
        }
        OUT_PX(0, R0.x, G0.x, B0.x)
        OUT_PX(1, R0.y, G0.y, B0.y)
        OUT_PX(2, R1.x, G1.x, B1.x)
        OUT_PX(3, R1.y, G1.y, B1.y)
        OUT_PX(4, R2.x, G2.x, B2.x)
        OUT_PX(5, R2.y, G2.y, B2.y)
        OUT_PX(6, R3.x, G3.x, B3.x)
        OUT_PX(7, R3.y, G3.y, B3.y)
#undef OUT_PX
    }
#undef PUBLISH
#undef COMPOSE
}

extern "C" void kernel_launch(void* const* d_in, const int* in_sizes, int n_in,
                              void* d_out, int out_size, void* d_ws, size_t ws_size,
                              hipStream_t stream) {
    const float* pos2d   = (const float*)d_in[0];
    const float* cov2d   = (const float*)d_in[1];
    const float* opacity = (const float*)d_in[2];
    const float* color   = (const float*)d_in[3];
    float* out = (float*)d_out;

    char* ws = (char*)d_ws;
    float4* a4 = (float4*)(ws);
    float4* b4 = (float4*)(ws + 65536);
    float*  c1 = (float*)(ws + 131072);
    unsigned long long* tm = (unsigned long long*)(ws + 147456);

    gs_preprocess<<<N_G / 8, 256, 0, stream>>>(pos2d, cov2d, opacity, color,
                                               a4, b4, c1, tm);
    gs_render<<<NTILES * 8, 512, 0, stream>>>(a4, b4, c1, tm, out);
}